// Round 10
// baseline (524.080 us; speedup 1.0000x reference)
//
#include <hip/hip_runtime.h>
#include <hip/hip_cooperative_groups.h>
namespace cg = cooperative_groups;

// Problem constants (fixed by reference)
constexpr int N_  = 10000;   // nodes (< 65536 -> u16 src)
constexpr int E_  = 320000;  // edges
constexpr int F1  = 33;      // input features
constexpr int H   = 32;      // hidden
constexpr int G   = 64;      // graphs
constexpr int CAP = 96;      // padded CSR slots/node (deg~Poisson(32), P(overflow)~1e-18/node)

// Cooperative-launch limit: ~43KB static LDS -> runtime validates 1 block/CU vs its 64KB
// shared budget -> max cooperative grid = 256. (512 failed to launch in R9.)
constexpr int GRID   = 256;
constexpr int SLICES = 32;
constexpr int CHUNKS = 8;        // GRID = SLICES * CHUNKS
constexpr int TILE   = 1280;     // nodes per (slice,chunk) block; 8*1280 = 10240 >= N_
constexpr int ITERS  = TILE / 32;   // 40 groups of 32 nodes per wave-quad pass
constexpr int PBLK   = N_ / 8;   // 1250 node-group tasks

// round-to-nearest-even f32 -> bf16 (low 16 bits)
__device__ __forceinline__ unsigned bf16r(float x) {
    unsigned u = __float_as_uint(x);
    return (u + 0x7FFFu + ((u >> 16) & 1u)) >> 16;
}

struct Params {
    const int* ei; const float* ea; const float* x; const int* batch;
    const float* A1; const float* B1; const float* Rw1; const float* bi1;
    const float* A2; const float* B2; const float* Rw2; const float* bi2;
    const float* A3; const float* B3; const float* Rw3; const float* bi3;
    const float* w1; const float* wb1; const float* w2; const float* wb2;
    int* counts; int* startsP; unsigned* metaU;
    unsigned* UVs; float* Rs; float* Hs;   // single reused buffers (slice-major)
    float* out;
};

// ---- agg phase: block = (slice s, TILE-node chunk); LDS = full per-slice UV table ----
__device__ __forceinline__ void agg_phase(unsigned* uvl, const Params& P, int bid, int tid) {
    int s = bid & 31, chunk = bid >> 5;
    int l = tid & 63, wav = tid >> 6, j0 = l & 7, nl = l >> 3;

    int cbase = chunk * TILE + wav * 8;
    int node = cbase + nl;
    int nc = min(node, N_ - 1);
    int dg = (node < N_) ? P.counts[nc] : 0;
    float rv = P.Rs[(size_t)s * N_ + nc];
    const unsigned* mr = P.metaU + (size_t)nc * CAP + j0;
    unsigned m0 = mr[0], m1 = mr[8], m2 = mr[16], m3 = mr[24], m4 = mr[32], m5 = mr[40];

    const unsigned* srcp = P.UVs + (size_t)s * N_;
    #pragma unroll
    for (int i = 0; i < 10; ++i) {
        int d4 = (i * 256 + tid) * 4;
        if (d4 + 4 <= N_) {
            uint4 t = *reinterpret_cast<const uint4*>(srcp + d4);
            *reinterpret_cast<uint4*>(&uvl[d4]) = t;
        }
    }
    __syncthreads();

    for (int it = 0; it < ITERS; ++it) {
        int nbase = cbase + 32;
        int nnode = nbase + nl;
        int nnc = min(nnode, N_ - 1);
        int ndg = 0; float nrv = 0.f;
        unsigned n0 = 0, n1 = 0, n2 = 0, n3 = 0, n4 = 0, n5 = 0;
        if (it < ITERS - 1) {
            ndg = (nnode < N_) ? P.counts[nnc] : 0;
            nrv = P.Rs[(size_t)s * N_ + nnc];
            const unsigned* nmr = P.metaU + (size_t)nnc * CAP + j0;
            n0 = nmr[0]; n1 = nmr[8]; n2 = nmr[16]; n3 = nmr[24]; n4 = nmr[32]; n5 = nmr[40];
        }

        int maxd = dg;
        maxd = max(maxd, __shfl_xor(maxd, 8));
        maxd = max(maxd, __shfl_xor(maxd, 16));
        maxd = max(maxd, __shfl_xor(maxd, 32));
        float acc = 0.f;
        auto slot = [&](int p, unsigned mv) {
            unsigned idx = min(mv & 0xFFFFu, (unsigned)(N_ - 1));
            unsigned w = uvl[idx];
            float t = fmaf(__uint_as_float(mv & 0xFFFF0000u),
                           __uint_as_float(w << 16),
                           __uint_as_float(w & 0xFFFF0000u));
            if (j0 + 8 * p < dg) acc += t;
        };
        if (maxd > 0)  slot(0, m0);
        if (maxd > 8)  slot(1, m1);
        if (maxd > 16) slot(2, m2);
        if (maxd > 24) slot(3, m3);
        if (maxd > 32) slot(4, m4);
        if (maxd > 40) slot(5, m5);
        if (maxd > 48) {
            for (int p = 6; 8 * p < maxd; ++p)
                slot(p, P.metaU[(size_t)nc * CAP + j0 + 8 * p]);
        }
        acc += __shfl_xor(acc, 1);
        acc += __shfl_xor(acc, 2);
        acc += __shfl_xor(acc, 4);
        float h = fmaxf(rv + acc, 0.f);
        if (j0 == 0 && node < N_) P.Hs[(size_t)s * N_ + node] = h;

        cbase = nbase; node = nnode; nc = nnc; dg = ndg; rv = nrv;
        m0 = n0; m1 = n1; m2 = n2; m3 = n3; m4 = n4; m5 = n5;
    }
}

// ---- pre phase (layers 2,3): U,V,R from slice-major h ----
__device__ __forceinline__ void pre_phase(const float* A, const float* Bm,
                                          const float* Rw, const float* bias,
                                          const Params& P, int bid, int tid,
                                          unsigned (*s_uv)[9], float (*s_r)[9]) {
    int grp = tid >> 5, f = tid & 31;
    int fo = tid >> 3, nl = tid & 7;
    for (int t = bid; t < PBLK; t += GRID) {
        int base8 = t * 8;
        int node = base8 + grp;
        float hv = P.Hs[(size_t)f * N_ + node];
        float u = 0.f, v = 0.f, r = bias[f];
        #pragma unroll
        for (int k = 0; k < H; ++k) {
            float hk = __shfl(hv, k, 32);
            u = fmaf(hk, A[k * H + f], u);
            v = fmaf(hk, Bm[k * H + f], v);
            r = fmaf(hk, Rw[k * H + f], r);
        }
        s_uv[f][grp] = bf16r(u) | (bf16r(v) << 16);
        s_r[f][grp]  = r;
        __syncthreads();
        P.UVs[(size_t)fo * N_ + base8 + nl] = s_uv[fo][nl];
        P.Rs [(size_t)fo * N_ + base8 + nl] = s_r [fo][nl];
        __syncthreads();
    }
}

// ---------------- the single cooperative kernel ----------------

__global__ __launch_bounds__(256) void k_mega(Params P) {
    cg::grid_group grid = cg::this_grid();
    int tid = threadIdx.x;
    int bid = blockIdx.x;
    int gtid = bid * 256 + tid;

    __shared__ __align__(16) unsigned uvl[N_];   // 40 KB agg table
    __shared__ unsigned s_uv[32][9];
    __shared__ float    s_r[32][9];

    // ---- phase 0: zero counts + startsP (ws is 0xAA-poisoned) ----
    for (int i = gtid; i < N_ + G; i += GRID * 256) {
        if (i < N_) P.counts[i] = 0; else P.startsP[i - N_] = 0;
    }
    grid.sync();

    // ---- phase 1: CSR build (edge grid-stride) + layer-1 precompute (task grid-stride) ----
    for (int e = gtid; e < E_; e += GRID * 256) {
        int s = P.ei[e];
        int d = P.ei[E_ + e];
        int pos = atomicAdd(&P.counts[d], 1);
        P.metaU[(size_t)d * CAP + pos] = (unsigned)s | (bf16r(P.ea[e]) << 16);
    }
    {
        int grp = tid >> 5, f = tid & 31;
        int fo = tid >> 3, nl = tid & 7;
        for (int t = bid; t < PBLK; t += GRID) {
            int base8 = t * 8;
            int node = base8 + grp;
            if (f == 0) {   // graph-boundary detection (batch sorted)
                int b = P.batch[node];
                int bp = (node == 0) ? -1 : P.batch[node - 1];
                if (b != bp) P.startsP[b] = node + 1;
            }
            float u = 0.f, v = 0.f, r = P.bi1[f];
            const float* xr = P.x + (size_t)node * F1;
            #pragma unroll
            for (int k = 0; k < F1; ++k) {
                float xv = xr[k];
                u = fmaf(xv, P.A1[k * H + f], u);
                v = fmaf(xv, P.B1[k * H + f], v);
                r = fmaf(xv, P.Rw1[k * H + f], r);
            }
            s_uv[f][grp] = bf16r(u) | (bf16r(v) << 16);
            s_r[f][grp]  = r;
            __syncthreads();
            P.UVs[(size_t)fo * N_ + base8 + nl] = s_uv[fo][nl];
            P.Rs [(size_t)fo * N_ + base8 + nl] = s_r [fo][nl];
            __syncthreads();
        }
    }
    grid.sync();

    // ---- layer 1 agg ----
    agg_phase(uvl, P, bid, tid);
    grid.sync();
    // ---- layer 2 ----
    pre_phase(P.A2, P.B2, P.Rw2, P.bi2, P, bid, tid, s_uv, s_r);
    grid.sync();
    agg_phase(uvl, P, bid, tid);
    grid.sync();
    // ---- layer 3 ----
    pre_phase(P.A3, P.B3, P.Rw3, P.bi3, P, bid, tid, s_uv, s_r);
    grid.sync();
    agg_phase(uvl, P, bid, tid);
    grid.sync();

    // ---- pooling + readout: 64 independent per-graph blocks, no atomics ----
    if (bid < G) {
        __shared__ int sst[G];
        __shared__ float ga[32], gm[32], gx[32];
        if (tid < G) sst[tid] = P.startsP[tid];
        __syncthreads();
        int g = bid;
        int sp = sst[g];
        int s = 0, e = 0;
        if (sp != 0) {
            s = sp - 1;
            e = N_;
            for (int j = g + 1; j < G; ++j)
                if (sst[j]) { e = sst[j] - 1; break; }
        }
        int f = tid >> 3, oct = tid & 7;
        float sum = 0.f, mx = 0.f;
        for (int n = s + oct; n < e; n += 8) {
            float w = P.Hs[(size_t)f * N_ + n];
            sum += w;
            mx = fmaxf(mx, w);
        }
        sum += __shfl_xor(sum, 1); mx = fmaxf(mx, __shfl_xor(mx, 1));
        sum += __shfl_xor(sum, 2); mx = fmaxf(mx, __shfl_xor(mx, 2));
        sum += __shfl_xor(sum, 4); mx = fmaxf(mx, __shfl_xor(mx, 4));
        if (oct == 0) {
            float c = fmaxf((float)(e - s), 1.0f);
            ga[f] = sum;
            gm[f] = sum / c;
            gx[f] = mx;
        }
        __syncthreads();
        if (tid < 32) {
            float hacc = P.wb1[tid];
            #pragma unroll
            for (int k = 0; k < H; ++k) {
                hacc = fmaf(ga[k], P.w1[k * H + tid], hacc);
                hacc = fmaf(gm[k], P.w1[(H + k) * H + tid], hacc);
                hacc = fmaf(gx[k], P.w1[(2 * H + k) * H + tid], hacc);
            }
            float hid = fmaxf(hacc, 0.f);
            float p0 = hid * P.w2[tid * 2 + 0];
            float p1 = hid * P.w2[tid * 2 + 1];
            #pragma unroll
            for (int offq = 16; offq; offq >>= 1) {
                p0 += __shfl_xor(p0, offq, 32);
                p1 += __shfl_xor(p1, offq, 32);
            }
            if (tid == 0) {
                float l0 = p0 + P.wb2[0], l1 = p1 + P.wb2[1];
                float m = fmaxf(l0, l1);
                float lse = m + logf(expf(l0 - m) + expf(l1 - m));
                P.out[g * 2 + 0] = l0 - lse;
                P.out[g * 2 + 1] = l1 - lse;
            }
        }
    }
}

// ---------------- launch ----------------

extern "C" void kernel_launch(void* const* d_in, const int* in_sizes, int n_in,
                              void* d_out, int out_size, void* d_ws, size_t ws_size,
                              hipStream_t stream) {
    char* ws = (char*)d_ws;
    size_t off = 0;
    auto alloc = [&](size_t bytes) -> void* {
        void* p = ws + off;
        off += (bytes + 255) & ~(size_t)255;
        return p;
    };

    Params P;
    P.ei    = (const int*)  d_in[1];
    P.ea    = (const float*)d_in[2];
    P.x     = (const float*)d_in[0];
    P.batch = (const int*)  d_in[3];
    P.A1 = (const float*)d_in[4];  P.B1 = (const float*)d_in[5];
    P.Rw1 = (const float*)d_in[6]; P.bi1 = (const float*)d_in[7];
    P.A2 = (const float*)d_in[8];  P.B2 = (const float*)d_in[9];
    P.Rw2 = (const float*)d_in[10]; P.bi2 = (const float*)d_in[11];
    P.A3 = (const float*)d_in[12]; P.B3 = (const float*)d_in[13];
    P.Rw3 = (const float*)d_in[14]; P.bi3 = (const float*)d_in[15];
    P.w1  = (const float*)d_in[16]; P.wb1 = (const float*)d_in[17];
    P.w2  = (const float*)d_in[18]; P.wb2 = (const float*)d_in[19];
    P.out = (float*)d_out;

    P.counts  = (int*)alloc(N_ * sizeof(int));
    P.startsP = (int*)alloc(G * sizeof(int));
    P.metaU   = (unsigned*)alloc((size_t)N_ * CAP * sizeof(unsigned));  // 3.84 MB
    P.UVs     = (unsigned*)alloc((size_t)H * N_ * sizeof(unsigned));    // 1.28 MB (reused)
    P.Rs      = (float*)   alloc((size_t)H * N_ * sizeof(float));       // 1.28 MB (reused)
    P.Hs      = (float*)   alloc((size_t)H * N_ * sizeof(float));       // 1.28 MB (reused)

    void* args[] = { &P };
    hipLaunchCooperativeKernel((void*)k_mega, dim3(GRID), dim3(256), args, 0, stream);
}

// Round 11
// 188.340 us; speedup vs baseline: 2.7826x; 2.7826x over previous
//
#include <hip/hip_runtime.h>

// Problem constants (fixed by reference)
constexpr int N_  = 10000;   // nodes (< 65536 -> u16 src)
constexpr int E_  = 320000;  // edges
constexpr int F1  = 33;      // input features
constexpr int H   = 32;      // hidden
constexpr int G   = 64;      // graphs
constexpr int CAP = 96;      // padded CSR slots/node (deg~Poisson(32), P(overflow)~1e-18/node)
constexpr int NB_ = 1280;    // node-blocks of 8 (covers 10240 >= N_)
constexpr int ROW = CAP * 8; // 768 dwords per node-block row in transposed meta

constexpr int EBLK = E_ / 256;   // 1250 edge blocks
constexpr int PBLK = N_ / 8;     // 1250 node-group tasks (8 nodes x 32 lanes)
constexpr int SLICES = 32;
constexpr int CHUNKS = 32;       // 1024 blocks total; 3 blocks/CU (LDS-limited) -> 12 waves/CU
constexpr int TILE   = 320;      // 32*320 = 10240 >= N_
constexpr int ITERS  = TILE / 32;

// round-to-nearest-even f32 -> bf16 (low 16 bits)
__device__ __forceinline__ unsigned bf16r(float x) {
    unsigned u = __float_as_uint(x);
    return (u + 0x7FFFu + ((u >> 16) & 1u)) >> 16;
}

// transposed meta slot address: node n, slot pos
__device__ __forceinline__ size_t mslot(int n, int pos) {
    return (size_t)(n >> 3) * ROW + (size_t)(pos >> 3) * 64 + (n & 7) * 8 + (pos & 7);
}

// ---------------- build: padded CSR (transposed) + layer-1 precompute ----------------
// meta2 layout: [nodeblk][p][nl][j0] -> a wave reads one slot-group as 64 consecutive dwords.

__global__ __launch_bounds__(256) void k_build_pre1(
        const int* __restrict__ ei, const float* __restrict__ ea,
        const float* __restrict__ x, const int* __restrict__ batch,
        const float* __restrict__ A, const float* __restrict__ Bm,
        const float* __restrict__ Rw, const float* __restrict__ bias,
        int* __restrict__ counts, unsigned* __restrict__ meta2,
        unsigned* __restrict__ UVs, float* __restrict__ Rs,
        int* __restrict__ startsP) {
    __shared__ unsigned s_uv[32][9];
    __shared__ float    s_r[32][9];
    if (blockIdx.x < EBLK) {
        int e = blockIdx.x * 256 + threadIdx.x;
        int s = ei[e];
        int d = ei[E_ + e];
        int pos = atomicAdd(&counts[d], 1);
        meta2[mslot(d, pos)] = (unsigned)s | (bf16r(ea[e]) << 16);
    } else {
        int base8 = (blockIdx.x - EBLK) * 8;
        int grp = threadIdx.x >> 5;
        int f = threadIdx.x & 31;
        int node = base8 + grp;
        if (f == 0) {   // graph-boundary detection (batch sorted)
            int b = batch[node];
            int bp = (node == 0) ? -1 : batch[node - 1];
            if (b != bp) startsP[b] = node + 1;
        }
        float u = 0.f, v = 0.f, r = bias[f];
        const float* xr = x + (size_t)node * F1;
        #pragma unroll
        for (int k = 0; k < F1; ++k) {
            float xv = xr[k];
            u = fmaf(xv, A[k * H + f], u);
            v = fmaf(xv, Bm[k * H + f], v);
            r = fmaf(xv, Rw[k * H + f], r);
        }
        s_uv[f][grp] = bf16r(u) | (bf16r(v) << 16);
        s_r[f][grp]  = r;
        __syncthreads();
        int fo = threadIdx.x >> 3;
        int nl = threadIdx.x & 7;
        UVs[(size_t)fo * N_ + base8 + nl] = s_uv[fo][nl];
        Rs [(size_t)fo * N_ + base8 + nl] = s_r [fo][nl];
    }
}

// ---------------- per-layer precompute from slice-major h ----------------

__global__ __launch_bounds__(256) void k_pre(
        const float* __restrict__ Hs,
        const float* __restrict__ A, const float* __restrict__ Bm,
        const float* __restrict__ Rw, const float* __restrict__ bias,
        unsigned* __restrict__ UVs, float* __restrict__ Rs) {
    __shared__ unsigned s_uv[32][9];
    __shared__ float    s_r[32][9];
    int base8 = blockIdx.x * 8;
    int grp = threadIdx.x >> 5;
    int f = threadIdx.x & 31;
    int node = base8 + grp;
    float hv = Hs[(size_t)f * N_ + node];
    float u = 0.f, v = 0.f, r = bias[f];
    #pragma unroll
    for (int k = 0; k < H; ++k) {
        float hk = __shfl(hv, k, 32);
        u = fmaf(hk, A[k * H + f], u);
        v = fmaf(hk, Bm[k * H + f], v);
        r = fmaf(hk, Rw[k * H + f], r);
    }
    s_uv[f][grp] = bf16r(u) | (bf16r(v) << 16);
    s_r[f][grp]  = r;
    __syncthreads();
    int fo = threadIdx.x >> 3;
    int nl = threadIdx.x & 7;
    UVs[(size_t)fo * N_ + base8 + nl] = s_uv[fo][nl];
    Rs [(size_t)fo * N_ + base8 + nl] = s_r [fo][nl];
}

// ---------------- LDS-sliced conv aggregation, coalesced transposed meta ----------------
// block = (slice s, 320-node chunk). LDS = full per-feature UV table (40 KB).
// wave iter: 6 coalesced 256B meta reads (2 lines each) + LDS gathers.

__global__ __launch_bounds__(256) void k_agg_lds(
        const int* __restrict__ counts, const unsigned* __restrict__ meta2,
        const unsigned* __restrict__ UVs, const float* __restrict__ Rs,
        float* __restrict__ Hs) {
    __shared__ __align__(16) unsigned uvl[N_];
    int s     = blockIdx.x & 31;
    int chunk = blockIdx.x >> 5;

    int l   = threadIdx.x & 63;
    int wav = threadIdx.x >> 6;      // 0..3
    int j0  = l & 7;                 // slot within group
    int nl  = l >> 3;                // node within wave (0..7)

    // ---- initial prefetch (overlaps LDS fill) ----
    int cbase = chunk * TILE + wav * 8;
    int node = cbase + nl;
    int nc = min(node, N_ - 1);
    int dg = (node < N_) ? counts[nc] : 0;
    float rv = Rs[(size_t)s * N_ + nc];
    const unsigned* mrow = meta2 + (size_t)(cbase >> 3) * ROW + l;
    unsigned m0 = mrow[0], m1 = mrow[64], m2 = mrow[128],
             m3 = mrow[192], m4 = mrow[256], m5 = mrow[320];

    // ---- fill LDS with this slice's UV table (coalesced 40 KB) ----
    const unsigned* srcp = UVs + (size_t)s * N_;
    #pragma unroll
    for (int i = 0; i < 10; ++i) {
        int d4 = (i * 256 + threadIdx.x) * 4;
        if (d4 + 4 <= N_) {
            uint4 t = *reinterpret_cast<const uint4*>(srcp + d4);
            *reinterpret_cast<uint4*>(&uvl[d4]) = t;
        }
    }
    __syncthreads();

    for (int it = 0; it < ITERS; ++it) {
        // ---- prefetch next group ----
        int nbase = cbase + 32;
        int nnode = nbase + nl;
        int nnc = min(nnode, N_ - 1);
        int ndg = 0; float nrv = 0.f;
        unsigned n0 = 0, n1 = 0, n2 = 0, n3 = 0, n4 = 0, n5 = 0;
        if (it < ITERS - 1) {
            ndg = (nnode < N_) ? counts[nnc] : 0;
            nrv = Rs[(size_t)s * N_ + nnc];
            const unsigned* nmr = meta2 + (size_t)(nbase >> 3) * ROW + l;
            n0 = nmr[0]; n1 = nmr[64]; n2 = nmr[128];
            n3 = nmr[192]; n4 = nmr[256]; n5 = nmr[320];
        }

        // ---- compute current group ----
        int maxd = dg;
        maxd = max(maxd, __shfl_xor(maxd, 8));
        maxd = max(maxd, __shfl_xor(maxd, 16));
        maxd = max(maxd, __shfl_xor(maxd, 32));
        float acc = 0.f;
        auto slot = [&](int p, unsigned mv) {
            unsigned idx = min(mv & 0xFFFFu, (unsigned)(N_ - 1));
            unsigned w = uvl[idx];
            float t = fmaf(__uint_as_float(mv & 0xFFFF0000u),   // a (bf16 hi)
                           __uint_as_float(w << 16),            // u
                           __uint_as_float(w & 0xFFFF0000u));   // v
            if (j0 + 8 * p < dg) acc += t;
        };
        if (maxd > 0)  slot(0, m0);
        if (maxd > 8)  slot(1, m1);
        if (maxd > 16) slot(2, m2);
        if (maxd > 24) slot(3, m3);
        if (maxd > 32) slot(4, m4);
        if (maxd > 40) slot(5, m5);
        if (maxd > 48) {                       // rare tail
            const unsigned* trow = meta2 + (size_t)(cbase >> 3) * ROW + l;
            for (int p = 6; 8 * p < maxd; ++p)
                slot(p, trow[p * 64]);
        }
        acc += __shfl_xor(acc, 1);
        acc += __shfl_xor(acc, 2);
        acc += __shfl_xor(acc, 4);
        float h = fmaxf(rv + acc, 0.f);
        if (j0 == 0 && node < N_) Hs[(size_t)s * N_ + node] = h;

        cbase = nbase; node = nnode; nc = nnc; dg = ndg; rv = nrv;
        m0 = n0; m1 = n1; m2 = n2; m3 = n3; m4 = n4; m5 = n5;
    }
}

// ---------------- per-graph pooling + readout: 64 independent blocks, NO atomics ----------

__global__ __launch_bounds__(256) void k_pool(
        const float* __restrict__ Hs, const int* __restrict__ startsP,
        const float* __restrict__ w1, const float* __restrict__ b1,
        const float* __restrict__ w2, const float* __restrict__ b2,
        float* __restrict__ out) {
    __shared__ int sst[G];
    __shared__ float ga[32], gm[32], gx[32];
    int tid = threadIdx.x;
    if (tid < G) sst[tid] = startsP[tid];
    __syncthreads();
    int g = blockIdx.x;
    int sp = sst[g];
    int s = 0, e = 0;
    if (sp != 0) {
        s = sp - 1;
        e = N_;
        for (int j = g + 1; j < G; ++j)
            if (sst[j]) { e = sst[j] - 1; break; }
    }
    int f = tid >> 3, oct = tid & 7;
    float sum = 0.f, mx = 0.f;
    for (int n = s + oct; n < e; n += 8) {
        float w = Hs[(size_t)f * N_ + n];
        sum += w;
        mx = fmaxf(mx, w);
    }
    sum += __shfl_xor(sum, 1); mx = fmaxf(mx, __shfl_xor(mx, 1));
    sum += __shfl_xor(sum, 2); mx = fmaxf(mx, __shfl_xor(mx, 2));
    sum += __shfl_xor(sum, 4); mx = fmaxf(mx, __shfl_xor(mx, 4));
    if (oct == 0) {
        float c = fmaxf((float)(e - s), 1.0f);
        ga[f] = sum;
        gm[f] = sum / c;
        gx[f] = mx;
    }
    __syncthreads();
    if (tid < 32) {
        float hacc = b1[tid];
        #pragma unroll
        for (int k = 0; k < H; ++k) {
            hacc = fmaf(ga[k], w1[k * H + tid], hacc);
            hacc = fmaf(gm[k], w1[(H + k) * H + tid], hacc);
            hacc = fmaf(gx[k], w1[(2 * H + k) * H + tid], hacc);
        }
        float hid = fmaxf(hacc, 0.f);
        float p0 = hid * w2[tid * 2 + 0];
        float p1 = hid * w2[tid * 2 + 1];
        #pragma unroll
        for (int offq = 16; offq; offq >>= 1) {
            p0 += __shfl_xor(p0, offq, 32);
            p1 += __shfl_xor(p1, offq, 32);
        }
        if (tid == 0) {
            float l0 = p0 + b2[0], l1 = p1 + b2[1];
            float m = fmaxf(l0, l1);
            float lse = m + logf(expf(l0 - m) + expf(l1 - m));
            out[g * 2 + 0] = l0 - lse;
            out[g * 2 + 1] = l1 - lse;
        }
    }
}

// ---------------- launch ----------------

extern "C" void kernel_launch(void* const* d_in, const int* in_sizes, int n_in,
                              void* d_out, int out_size, void* d_ws, size_t ws_size,
                              hipStream_t stream) {
    const float* x      = (const float*)d_in[0];
    const int*   ei     = (const int*)  d_in[1];
    const float* ea     = (const float*)d_in[2];
    const int*   batch  = (const int*)  d_in[3];
    const float* nn_w1  = (const float*)d_in[4];
    const float* nn_b1  = (const float*)d_in[5];
    const float* root1  = (const float*)d_in[6];
    const float* bias1  = (const float*)d_in[7];
    const float* nn_w2  = (const float*)d_in[8];
    const float* nn_b2  = (const float*)d_in[9];
    const float* root2  = (const float*)d_in[10];
    const float* bias2  = (const float*)d_in[11];
    const float* nn_w3  = (const float*)d_in[12];
    const float* nn_b3  = (const float*)d_in[13];
    const float* root3  = (const float*)d_in[14];
    const float* bias3  = (const float*)d_in[15];
    const float* lin1_w = (const float*)d_in[16];
    const float* lin1_b = (const float*)d_in[17];
    const float* lin2_w = (const float*)d_in[18];
    const float* lin2_b = (const float*)d_in[19];
    float* out = (float*)d_out;

    char* ws = (char*)d_ws;
    size_t off = 0;
    auto alloc = [&](size_t bytes) -> void* {
        void* p = ws + off;
        off += (bytes + 255) & ~(size_t)255;
        return p;
    };
    // zero-init chunk: counts | startsP
    const size_t zbytes = N_ * sizeof(int) + G * sizeof(int);
    char* zchunk = (char*)alloc(zbytes);
    int*  counts  = (int*)zchunk;
    int*  startsP = (int*)(zchunk + N_ * sizeof(int));
    unsigned* meta2 = (unsigned*)alloc((size_t)NB_ * ROW * sizeof(unsigned)); // 3.93 MB
    unsigned* UVs1 = (unsigned*)alloc((size_t)H * N_ * sizeof(unsigned));
    unsigned* UVs2 = (unsigned*)alloc((size_t)H * N_ * sizeof(unsigned));
    unsigned* UVs3 = (unsigned*)alloc((size_t)H * N_ * sizeof(unsigned));
    float* Rs1 = (float*)alloc((size_t)H * N_ * sizeof(float));
    float* Rs2 = (float*)alloc((size_t)H * N_ * sizeof(float));
    float* Rs3 = (float*)alloc((size_t)H * N_ * sizeof(float));
    float* h1  = (float*)alloc((size_t)H * N_ * sizeof(float));   // slice-major
    float* h2  = (float*)alloc((size_t)H * N_ * sizeof(float));
    float* h3  = (float*)alloc((size_t)H * N_ * sizeof(float));

    hipMemsetAsync(zchunk, 0, zbytes, stream);

    k_build_pre1<<<EBLK + PBLK, 256, 0, stream>>>(ei, ea, x, batch,
                                                  nn_w1, nn_b1, root1, bias1,
                                                  counts, meta2, UVs1, Rs1, startsP);

    k_agg_lds<<<SLICES * CHUNKS, 256, 0, stream>>>(counts, meta2, UVs1, Rs1, h1);
    k_pre    <<<PBLK, 256, 0, stream>>>(h1, nn_w2, nn_b2, root2, bias2, UVs2, Rs2);
    k_agg_lds<<<SLICES * CHUNKS, 256, 0, stream>>>(counts, meta2, UVs2, Rs2, h2);
    k_pre    <<<PBLK, 256, 0, stream>>>(h2, nn_w3, nn_b3, root3, bias3, UVs3, Rs3);
    k_agg_lds<<<SLICES * CHUNKS, 256, 0, stream>>>(counts, meta2, UVs3, Rs3, h3);

    k_pool<<<G, 256, 0, stream>>>(h3, startsP, lin1_w, lin1_b, lin2_w, lin2_b, out);
}